// Round 11
// baseline (387.876 us; speedup 1.0000x reference)
//
#include <hip/hip_runtime.h>
#include <math.h>

typedef _Float16 half8 __attribute__((ext_vector_type(8)));
typedef float f32x4 __attribute__((ext_vector_type(4)));

__device__ inline uint splitpack(float v) {
    _Float16 h = (_Float16)v;
    float r = v - (float)h;
    _Float16 l = (_Float16)r;
    return (uint)__builtin_bit_cast(unsigned short, h) |
           ((uint)__builtin_bit_cast(unsigned short, l) << 16);
}
__device__ inline _Float16 lo16h(uint u) { return __builtin_bit_cast(_Float16, (unsigned short)(u & 0xffffu)); }
__device__ inline _Float16 hi16h(uint u) { return __builtin_bit_cast(_Float16, (unsigned short)(u >> 16)); }
__device__ inline uint packhh(_Float16 a, _Float16 b) {
    return (uint)__builtin_bit_cast(unsigned short, a) |
           ((uint)__builtin_bit_cast(unsigned short, b) << 16);
}
__device__ inline float dpp_max8(float v) {
    int x = __builtin_amdgcn_mov_dpp(__builtin_bit_cast(int, v), 0x128, 0xf, 0xf, true);
    return fmaxf(v, __builtin_bit_cast(float, x));
}

// ---------------- fused conv1+conv2: x:[N,3,32,32] -> p2:[N,400] fp32 ----------------
// conv1 phase: round-10 structure verbatim, but pooled outputs go to LDS (conv2's layout).
// conv2 phase: round-10 inner loop verbatim, reading p1 from LDS (no global round-trip).
__global__ __launch_bounds__(256) void k_conv12(const float* __restrict__ x,
                                                const float* __restrict__ w1,
                                                const float* __restrict__ b1,
                                                const float* __restrict__ w2,
                                                const float* __restrict__ b2,
                                                float* __restrict__ p2) {
    __shared__ uint simg[6720];    // conv1 images: 2 * 3 planes * 32 rows * 35 dw (26.9 KB)
    __shared__ uint p1l[2520];     // p1 in conv2 layout: 2 imgs * [6][14x15] (10.1 KB)
    __shared__ uint sB2[2560];     // conv2 B fragments (10.2 KB)
    __shared__ float sb2[16];
    const int tid  = threadIdx.x;
    const int lane = tid & 63;
    const int wv   = tid >> 6;
    const int n0   = blockIdx.x * 2;

    const int colb = lane & 15;
    const int c  = colb & 7, dx = colb >> 3;
    const int g  = lane >> 4;
    const int qr = g;

    // conv1 B fragments in registers
    half8 bh[3], bl[3];
    #pragma unroll
    for (int ks = 0; ks < 3; ++ks)
        #pragma unroll
        for (int jj = 0; jj < 8; ++jj) {
            int pi = jj >> 1, e = jj & 1;
            int rho = g * 4 + pi;
            float val = 0.f;
            if (rho < 15 && c < 6) {
                int ci = rho / 5, ky = rho % 5;
                int kx = ks * 2 + e - dx;
                if (kx >= 0 && kx < 5) val = w1[c * 75 + ci * 25 + ky * 5 + kx];
            }
            _Float16 hh = (_Float16)val;
            bh[ks][jj] = hh;
            bl[ks][jj] = (_Float16)(val - (float)hh);
        }
    const float bias1 = (c < 6) ? b1[c] : 0.f;

    // stage conv1 images (row-interleaved split-fp16)
    for (int i = tid; i < 1536; i += 256) {
        int im = i / 768;
        int rem = i - im * 768;
        int plane = rem >> 8, rr = (rem & 255) >> 3, f = rem & 7;
        float4 v = *(const float4*)(x + ((size_t)(n0 + im) * 3 + plane) * 1024 + rr * 32 + f * 4);
        _Float16 h0 = (_Float16)v.x, h1 = (_Float16)v.y, h2 = (_Float16)v.z, h3 = (_Float16)v.w;
        _Float16 l0 = (_Float16)(v.x - (float)h0), l1 = (_Float16)(v.y - (float)h1);
        _Float16 l2 = (_Float16)(v.z - (float)h2), l3 = (_Float16)(v.w - (float)h3);
        int base = im * 3360 + plane * 1120 + rr * 35 + f * 2;
        simg[base]      = packhh(h0, h1);
        simg[base + 1]  = packhh(h2, h3);
        simg[base + 16] = packhh(l0, l1);
        simg[base + 17] = packhh(l2, l3);
    }
    // stage conv2 weight fragments (independent of conv1 phase)
    for (int p = tid; p < 320; p += 256) {
        int ks = p >> 6, l = p & 63;
        int nn = l & 15, gg = l >> 4;
        #pragma unroll
        for (int j = 0; j < 8; ++j) {
            int k = ks * 32 + gg * 8 + j;
            float wv_ = (k < 150) ? w2[nn * 150 + k] : 0.f;
            sB2[p * 8 + j] = splitpack(wv_);
        }
    }
    if (tid < 16) sb2[tid] = b2[tid];
    __syncthreads();

    // ---------------- conv1 main (round-10 verbatim, stores -> LDS) ----------------
    int poff[4];
    #pragma unroll
    for (int pi = 0; pi < 4; ++pi) {
        int rho = g * 4 + pi;
        if (rho > 14) rho = 14;
        poff[pi] = (rho / 5) * 1120 + (rho % 5) * 35;
    }

    for (int t0 = wv; t0 < 50; t0 += 8) {
        const int t1 = (t0 + 4 < 50) ? (t0 + 4) : t0;
        const int im0 = (t0 >= 25) ? 1 : 0, tl0 = t0 - im0 * 25;
        const int im1 = (t1 >= 25) ? 1 : 0, tl1 = t1 - im1 * 25;
        int r0c = tl0 * 16 + colb; if (r0c > 391) r0c = 391;
        int r1c = tl1 * 16 + colb; if (r1c > 391) r1c = 391;
        int qx0 = (r0c * 586) >> 14, yy0 = r0c - qx0 * 28;
        int qx1 = (r1c * 586) >> 14, yy1 = r1c - qx1 * 28;
        const uint* base0 = simg + im0 * 3360 + yy0 * 35 + qx0;
        const uint* base1 = simg + im1 * 3360 + yy1 * 35 + qx1;

        f32x4 A0[2] = {{0.f,0.f,0.f,0.f},{0.f,0.f,0.f,0.f}};
        f32x4 A1[2] = {{0.f,0.f,0.f,0.f},{0.f,0.f,0.f,0.f}};
        int c0 = 0, c1 = 0;
        #pragma unroll
        for (int ks = 0; ks < 3; ++ks) {
            uint h0[4], l0[4], h1[4], l1[4];
            #pragma unroll
            for (int pi = 0; pi < 4; ++pi) {
                const uint* a0p = base0 + poff[pi];
                const uint* a1p = base1 + poff[pi];
                h0[pi] = a0p[ks];  l0[pi] = a0p[16 + ks];
                h1[pi] = a1p[ks];  l1[pi] = a1p[16 + ks];
            }
            uint4 hv0; hv0.x = h0[0]; hv0.y = h0[1]; hv0.z = h0[2]; hv0.w = h0[3];
            uint4 lv0; lv0.x = l0[0]; lv0.y = l0[1]; lv0.z = l0[2]; lv0.w = l0[3];
            uint4 hv1; hv1.x = h1[0]; hv1.y = h1[1]; hv1.z = h1[2]; hv1.w = h1[3];
            uint4 lv1; lv1.x = l1[0]; lv1.y = l1[1]; lv1.z = l1[2]; lv1.w = l1[3];
            half8 ah0 = __builtin_bit_cast(half8, hv0);
            half8 al0 = __builtin_bit_cast(half8, lv0);
            half8 ah1 = __builtin_bit_cast(half8, hv1);
            half8 al1 = __builtin_bit_cast(half8, lv1);
            A0[c0 & 1] = __builtin_amdgcn_mfma_f32_16x16x32_f16(ah0, bh[ks], A0[c0 & 1], 0, 0, 0); ++c0;
            A1[c1 & 1] = __builtin_amdgcn_mfma_f32_16x16x32_f16(ah1, bh[ks], A1[c1 & 1], 0, 0, 0); ++c1;
            A0[c0 & 1] = __builtin_amdgcn_mfma_f32_16x16x32_f16(ah0, bl[ks], A0[c0 & 1], 0, 0, 0); ++c0;
            A1[c1 & 1] = __builtin_amdgcn_mfma_f32_16x16x32_f16(ah1, bl[ks], A1[c1 & 1], 0, 0, 0); ++c1;
            A0[c0 & 1] = __builtin_amdgcn_mfma_f32_16x16x32_f16(al0, bh[ks], A0[c0 & 1], 0, 0, 0); ++c0;
            A1[c1 & 1] = __builtin_amdgcn_mfma_f32_16x16x32_f16(al1, bh[ks], A1[c1 & 1], 0, 0, 0); ++c1;
        }
        {
            f32x4 acc;
            #pragma unroll
            for (int i = 0; i < 4; ++i) acc[i] = A0[0][i] + A0[1][i];
            float p01 = dpp_max8(fmaxf(acc[0], acc[1]));
            float p23 = dpp_max8(fmaxf(acc[2], acc[3]));
            if (dx == 0 && c < 6) {
                uint* outb = p1l + im0 * 1260 + c * 210;
                int r0 = tl0 * 16 + qr * 4;
                if (r0 + 1 < 392) {
                    int qxa = (r0 * 586) >> 14, ya = r0 - qxa * 28;
                    outb[(ya >> 1) * 15 + qxa] = splitpack(fmaxf(p01 + bias1, 0.f));
                }
                int r2 = r0 + 2;
                if (r2 + 1 < 392) {
                    int qxb = (r2 * 586) >> 14, yb = r2 - qxb * 28;
                    outb[(yb >> 1) * 15 + qxb] = splitpack(fmaxf(p23 + bias1, 0.f));
                }
            }
        }
        if (t1 != t0) {
            f32x4 acc;
            #pragma unroll
            for (int i = 0; i < 4; ++i) acc[i] = A1[0][i] + A1[1][i];
            float p01 = dpp_max8(fmaxf(acc[0], acc[1]));
            float p23 = dpp_max8(fmaxf(acc[2], acc[3]));
            if (dx == 0 && c < 6) {
                uint* outb = p1l + im1 * 1260 + c * 210;
                int r0 = tl1 * 16 + qr * 4;
                if (r0 + 1 < 392) {
                    int qxa = (r0 * 586) >> 14, ya = r0 - qxa * 28;
                    outb[(ya >> 1) * 15 + qxa] = splitpack(fmaxf(p01 + bias1, 0.f));
                }
                int r2 = r0 + 2;
                if (r2 + 1 < 392) {
                    int qxb = (r2 * 586) >> 14, yb = r2 - qxb * 28;
                    outb[(yb >> 1) * 15 + qxb] = splitpack(fmaxf(p23 + bias1, 0.f));
                }
            }
        }
    }
    __syncthreads();

    // ---------------- conv2 main (round-10 inner verbatim, 14 tile-tasks over 4 waves) ----------------
    const int qw2 = (lane & 15) >> 2;
    const int dy2 = (lane >> 1) & 1, dxx2 = lane & 1;
    int offs2[40];
    #pragma unroll
    for (int ks = 0; ks < 5; ++ks)
        #pragma unroll
        for (int j = 0; j < 8; ++j) {
            int k = ks * 32 + g * 8 + j;
            int o = 0;
            if (k < 150) { int ci = k / 25, r = k % 25; o = ci * 210 + (r / 5) * 15 + (r % 5); }
            offs2[ks * 8 + j] = o;
        }
    half8 bh2[5], bl2[5];
    #pragma unroll
    for (int ks = 0; ks < 5; ++ks)
        #pragma unroll
        for (int j = 0; j < 8; ++j) {
            uint u = sB2[(ks * 64 + lane) * 8 + j];
            bh2[ks][j] = lo16h(u); bl2[ks][j] = hi16h(u);
        }
    const int cc = lane & 15;
    const float bias2 = sb2[cc];

    for (int tt = wv; tt < 14; tt += 4) {
        const int im = tt / 7, t = tt - im * 7;
        const uint* img = p1l + im * 1260;
        int qa = t * 4 + qw2; if (qa > 24) qa = 24;
        int qy = qa / 5, qx = qa % 5;
        int base = (2 * qy + dy2) * 15 + (2 * qx + dxx2);
        f32x4 acc2[2] = {{0.f,0.f,0.f,0.f},{0.f,0.f,0.f,0.f}};
        int pp = 0;
        #pragma unroll
        for (int ks = 0; ks < 5; ++ks) {
            uint up[8];
            #pragma unroll
            for (int j = 0; j < 8; ++j) up[j] = img[base + offs2[ks * 8 + j]];
            half8 ah, al;
            #pragma unroll
            for (int j = 0; j < 8; ++j) { ah[j] = lo16h(up[j]); al[j] = hi16h(up[j]); }
            acc2[pp & 1] = __builtin_amdgcn_mfma_f32_16x16x32_f16(ah, bh2[ks], acc2[pp & 1], 0, 0, 0); ++pp;
            acc2[pp & 1] = __builtin_amdgcn_mfma_f32_16x16x32_f16(ah, bl2[ks], acc2[pp & 1], 0, 0, 0); ++pp;
            acc2[pp & 1] = __builtin_amdgcn_mfma_f32_16x16x32_f16(al, bh2[ks], acc2[pp & 1], 0, 0, 0); ++pp;
        }
        int qc = t * 4 + qr;
        if (qc < 25) {
            float m = fmaxf(fmaxf(acc2[0][0] + acc2[1][0], acc2[0][1] + acc2[1][1]),
                            fmaxf(acc2[0][2] + acc2[1][2], acc2[0][3] + acc2[1][3]));
            p2[(size_t)(n0 + im) * 400 + cc * 25 + qc] = fmaxf(m + bias2, 0.f);
        }
    }
}

// ---------------- fc1: [N,400] @ [120,400]^T + relu -> h1:[N,120] ----------------
__global__ __launch_bounds__(256) void k_fc1(const float* __restrict__ p2,
                                             const float* __restrict__ w,
                                             const float* __restrict__ b,
                                             float* __restrict__ h1) {
    __shared__ float sa[64 * 100];
    __shared__ float swt[120 * 101];
    const int tid = threadIdx.x;
    const int n0 = blockIdx.x * 64;
    const int tc = tid % 30, tr = tid / 30;
    float acc[8][4];
    #pragma unroll
    for (int i = 0; i < 8; ++i)
        #pragma unroll
        for (int j = 0; j < 4; ++j) acc[i][j] = 0.f;

    for (int kt = 0; kt < 4; ++kt) {
        __syncthreads();
        for (int i = tid; i < 1600; i += 256) {
            int r = i / 25, k4 = (i % 25) * 4;
            float4 v = *(const float4*)(p2 + (size_t)(n0 + r) * 400 + kt * 100 + k4);
            *(float4*)(sa + r * 100 + k4) = v;
        }
        for (int i = tid; i < 3000; i += 256) {
            int c = i / 25, k4 = (i % 25) * 4;
            float4 v = *(const float4*)(w + (size_t)c * 400 + kt * 100 + k4);
            float* d = swt + c * 101 + k4;
            d[0] = v.x; d[1] = v.y; d[2] = v.z; d[3] = v.w;
        }
        __syncthreads();
        if (tr < 8) {
            #pragma unroll 4
            for (int k = 0; k < 100; ++k) {
                float av[8], wv[4];
                #pragma unroll
                for (int i = 0; i < 8; ++i) av[i] = sa[(tr * 8 + i) * 100 + k];
                #pragma unroll
                for (int j = 0; j < 4; ++j) wv[j] = swt[(tc * 4 + j) * 101 + k];
                #pragma unroll
                for (int i = 0; i < 8; ++i)
                    #pragma unroll
                    for (int j = 0; j < 4; ++j) acc[i][j] = fmaf(av[i], wv[j], acc[i][j]);
            }
        }
    }
    if (tr < 8) {
        #pragma unroll
        for (int j = 0; j < 4; ++j) {
            const int o = tc * 4 + j;
            const float bo = b[o];
            #pragma unroll
            for (int i = 0; i < 8; ++i) {
                const int rr = n0 + tr * 8 + i;
                h1[(size_t)rr * 120 + o] = fmaxf(acc[i][j] + bo, 0.f);
            }
        }
    }
}

// ---------------- compose: C[e][o][d] = sum_j head_w[o][j]*expert_w[e][j][d] ----------------
__global__ __launch_bounds__(256) void k_compose(const float* __restrict__ ew,
                                                 const float* __restrict__ eb,
                                                 const float* __restrict__ hw,
                                                 float* __restrict__ C,
                                                 float* __restrict__ hb2) {
    __shared__ float shw[840];
    __shared__ float seb[672];
    const int e = blockIdx.x, tid = threadIdx.x;
    for (int i = tid; i < 840; i += 256) shw[i] = hw[i];
    for (int i = tid; i < 672; i += 256) seb[i] = eb[i];
    __syncthreads();
    for (int i = tid; i < 840; i += 256) {
        int o = i / 84, d = i % 84;
        float s = 0.f;
        for (int j = 0; j < 84; ++j)
            s = fmaf(shw[o * 84 + j], ew[((size_t)e * 84 + j) * 84 + d], s);
        C[e * 840 + i] = s;
    }
    if (tid < 10) {
        float s = 0.f;
        for (int j = 0; j < 84; ++j) s = fmaf(shw[tid * 84 + j], seb[e * 84 + j], s);
        hb2[e * 10 + tid] = s;
    }
}

// ---------------- tail: fc2+relu, gate, top2-softmax, MoE(composed)+head ----------------
__global__ __launch_bounds__(256) void k_tail(const float* __restrict__ h1,
                                              const float* __restrict__ f2w,
                                              const float* __restrict__ f2b,
                                              const float* __restrict__ gw,
                                              const float* __restrict__ Cw,
                                              const float* __restrict__ hb2,
                                              const float* __restrict__ headb,
                                              float* __restrict__ out) {
    __shared__ float sh1[64 * 120];
    __shared__ float sfw[84 * 121];
    __shared__ float sfb[84];
    __shared__ float sgw[672];
    __shared__ float sh[64 * 85];
    __shared__ float sC[6800];
    __shared__ float shb2[80];
    __shared__ float shb[10];
    __shared__ float slog[64 * 9];
    __shared__ float swt[128];
    __shared__ int   sei[128];
    const int tid = threadIdx.x;
    const int n0 = blockIdx.x * 64;

    {
        const float4* g = (const float4*)(h1 + (size_t)n0 * 120);
        float4* s = (float4*)sh1;
        for (int i = tid; i < 1920; i += 256) s[i] = g[i];
    }
    for (int i = tid; i < 2520; i += 256) {
        int o = i / 30, k4 = (i % 30) * 4;
        float4 v = *(const float4*)(f2w + (size_t)o * 120 + k4);
        float* d = sfw + o * 121 + k4;
        d[0] = v.x; d[1] = v.y; d[2] = v.z; d[3] = v.w;
    }
    for (int i = tid; i < 6720; i += 256) sC[(i / 84) * 85 + (i % 84)] = Cw[i];
    for (int i = tid; i < 672; i += 256) sgw[i] = gw[i];
    if (tid < 84) sfb[tid] = f2b[tid];
    if (tid < 80) shb2[tid] = hb2[tid];
    if (tid < 10) shb[tid] = headb[tid];
    __syncthreads();

    for (int i = tid; i < 5376; i += 256) {
        const int t = i / 84, o = i % 84;
        const float* a = sh1 + t * 120;
        const float* wr = sfw + o * 121;
        float s = 0.f;
        #pragma unroll 8
        for (int k = 0; k < 120; ++k) s = fmaf(a[k], wr[k], s);
        sh[t * 85 + o] = fmaxf(s + sfb[o], 0.f);
    }
    __syncthreads();

    for (int i = tid; i < 512; i += 256) {
        const int t = i / 8, e = i % 8;
        const float* a = sh + t * 85;
        float s = 0.f;
        #pragma unroll 4
        for (int d = 0; d < 84; ++d) s = fmaf(a[d], sgw[d * 8 + e], s);
        slog[t * 9 + e] = s;
    }
    __syncthreads();

    if (tid < 64) {
        const float* l = slog + tid * 9;
        float m1 = l[0]; int i1 = 0;
        #pragma unroll
        for (int e = 1; e < 8; ++e) if (l[e] > m1) { m1 = l[e]; i1 = e; }
        float m2 = -1e30f; int i2 = 0;
        #pragma unroll
        for (int e = 0; e < 8; ++e) if (e != i1 && l[e] > m2) { m2 = l[e]; i2 = e; }
        const float r = expf(m2 - m1);
        const float inv = 1.f / (1.f + r);
        swt[tid * 2] = inv; swt[tid * 2 + 1] = r * inv;
        sei[tid * 2] = i1; sei[tid * 2 + 1] = i2;
    }
    __syncthreads();

    for (int i = tid; i < 640; i += 256) {
        const int t = i / 10, o = i % 10;
        const float* a = sh + t * 85;
        const float w0 = swt[t * 2], w1 = swt[t * 2 + 1];
        const int e0 = sei[t * 2], e1 = sei[t * 2 + 1];
        const float* c0 = sC + (e0 * 10 + o) * 85;
        const float* c1 = sC + (e1 * 10 + o) * 85;
        float s0 = 0.f, s1 = 0.f;
        #pragma unroll 4
        for (int d = 0; d < 84; ++d) {
            s0 = fmaf(a[d], c0[d], s0);
            s1 = fmaf(a[d], c1[d], s1);
        }
        out[(size_t)(n0 + t) * 10 + o] =
            shb[o] + w0 * (s0 + shb2[e0 * 10 + o]) + w1 * (s1 + shb2[e1 * 10 + o]);
    }
}

extern "C" void kernel_launch(void* const* d_in, const int* in_sizes, int n_in,
                              void* d_out, int out_size, void* d_ws, size_t ws_size,
                              hipStream_t stream) {
    const float* x   = (const float*)d_in[0];
    const float* c1w = (const float*)d_in[1];
    const float* c1b = (const float*)d_in[2];
    const float* c2w = (const float*)d_in[3];
    const float* c2b = (const float*)d_in[4];
    const float* f1w = (const float*)d_in[5];
    const float* f1b = (const float*)d_in[6];
    const float* f2w = (const float*)d_in[7];
    const float* f2b = (const float*)d_in[8];
    const float* gw  = (const float*)d_in[9];
    const float* ew  = (const float*)d_in[10];
    const float* eb  = (const float*)d_in[11];
    const float* hw  = (const float*)d_in[12];
    const float* hb  = (const float*)d_in[13];
    float* out = (float*)d_out;

    const int N = in_sizes[0] / 3072;   // 16384

    float* ws = (float*)d_ws;
    float* p2  = ws;                           // N*400
    float* h1  = p2 + (size_t)N * 400;         // N*120
    float* C   = h1 + (size_t)N * 120;         // 6720
    float* hb2 = C + 6720;                     // 80

    k_conv12<<<N / 2, 256, 0, stream>>>(x, c1w, c1b, c2w, c2b, p2);
    k_fc1<<<N / 64, 256, 0, stream>>>(p2, f1w, f1b, h1);
    k_compose<<<8, 256, 0, stream>>>(ew, eb, hw, C, hb2);
    k_tail<<<N / 64, 256, 0, stream>>>(h1, f2w, f2b, gw, C, hb2, hb, out);
}